// Round 12
// baseline (112.030 us; speedup 1.0000x reference)
//
#include <hip/hip_runtime.h>
#include <hip/hip_bf16.h>
#include <math.h>

#define B_  2
#define S_  2048
#define H_  16
#define D_  64

typedef __attribute__((ext_vector_type(8))) short bf16x8_t;
typedef __attribute__((ext_vector_type(4))) float f32x4_t;

__device__ __forceinline__ unsigned short f2bf(float f) {
    __hip_bfloat16 h = __float2bfloat16(f);
    return __builtin_bit_cast(unsigned short, h);
}
__device__ __forceinline__ float bf2f(unsigned short u) {
    unsigned int x = ((unsigned int)u) << 16;
    return __builtin_bit_cast(float, x);
}

// xPos rotation factors for pair index i (0..31) at position pos (proven chain).
__device__ __forceinline__ void rotpair(int i, float pos, float& cs_s, float& sn_s, bool down) {
    float bsc  = (2.0f * (float)i + 25.6f) / 89.6f;
    float xsc  = exp2f(log2f(bsc) * pos * (1.0f / 512.0f));
    float invf = exp2f(-(float)i * (13.287712379549449f / 32.0f));
    float ang  = pos * invf;
    float kq = rintf(ang * 0.15915494309189535f);
    float rr = fmaf(kq, -6.2831853071795865f, ang);
    float sn = sinf(rr), cs = cosf(rr);
    float sc = down ? (1.0f / xsc) : xsc;
    cs_s = cs * sc; sn_s = sn * sc;
}

// ---------------- kernel 1: gkv — K-rot (register-hoisted) + transposes + per-chunk G ----
// R12: R11's gkv WITHOUT the atomic-tail scan (R11 post-mortem: intra-kernel
// cross-block Gg->scan handoff raced across XCD L2s — G16. Bulk visibility is
// only trusted at kernel boundaries in this harness). K-hoist kept: K loads +
// rotation into registers at the top so HBM latency + TRANS chains overlap the
// V stage/pack phases. Everything else verbatim R10 gkv.
__global__ __launch_bounds__(256) void gkv_kernel(const float* __restrict__ K,
                                                  const float* __restrict__ V,
                                                  unsigned short* __restrict__ kb,
                                                  unsigned short* __restrict__ vt,
                                                  unsigned short* __restrict__ Gg) {
    __shared__ float tileF[64 * 65];
    __shared__ __align__(16) unsigned short vtile[64 * 72];
    __shared__ __align__(16) unsigned short ktile[64 * 72];
    int t = threadIdx.x;
    int idx = blockIdx.x;
    int bh = idx >> 5, j = idx & 31;
    int b = bh >> 4, hh = bh & 15;
    int s0 = j * 64;
    int d = t >> 2, c = t & 3;

    float lnv = -3.4657359027997265f + (float)hh * (-0.18483924814931874f);
    float l2g = log2f(1.0f - expf(lnv));

    // ---- phase 0a: issue V loads -> registers (consumed first)
    float4 vreg[4];
#pragma unroll
    for (int it = 0; it < 4; ++it) {
        int f  = it * 256 + t;
        int sl = f >> 4, d4 = f & 15;
        vreg[it] = *(const float4*)(V + ((long)(b * S_ + s0 + sl)) * 1024 + hh * 64 + d4 * 4);
    }
    // ---- phase 0b: K loads + INLINE rotation -> registers (+ kb store);
    //      latency/TRANS overlap the V phases below
    float kreg[4][4];
#pragma unroll
    for (int it = 0; it < 4; ++it) {
        int f  = it * 256 + t;
        int sl = f >> 4, d4 = f & 15;
        float pos = (float)(s0 + sl);
        long a = ((long)(b * S_ + s0 + sl)) * 1024 + hh * 64 + d4 * 4;
        float4 xk = *(const float4*)(K + a);
        float gsi = exp2f(-pos * l2g);
        float c0, s0f, c1, s1f;
        rotpair(2 * d4 + 0, pos, c0, s0f, true);
        rotpair(2 * d4 + 1, pos, c1, s1f, true);
        float ck0 = c0 * gsi, sk0 = s0f * gsi;
        float ck1 = c1 * gsi, sk1 = s1f * gsi;
        kreg[it][0] = xk.x * ck0 - xk.y * sk0;
        kreg[it][1] = xk.y * ck0 + xk.x * sk0;
        kreg[it][2] = xk.z * ck1 - xk.w * sk1;
        kreg[it][3] = xk.w * ck1 + xk.z * sk1;
        *(uint2*)(kb + a) = make_uint2((unsigned)f2bf(kreg[it][0]) | ((unsigned)f2bf(kreg[it][1]) << 16),
                                       (unsigned)f2bf(kreg[it][2]) | ((unsigned)f2bf(kreg[it][3]) << 16));
    }
    // ---- V -> tileF
#pragma unroll
    for (int it = 0; it < 4; ++it) {
        int f  = it * 256 + t;
        int sl = f >> 4, d4 = f & 15;
        tileF[sl * 65 + d4 * 4 + 0] = vreg[it].x;
        tileF[sl * 65 + d4 * 4 + 1] = vreg[it].y;
        tileF[sl * 65 + d4 * 4 + 2] = vreg[it].z;
        tileF[sl * 65 + d4 * 4 + 3] = vreg[it].w;
    }
    __syncthreads();
    // ---- pack V^T -> vtile + global vt [proven]
    {
        unsigned int pk[8];
#pragma unroll
        for (int jj = 0; jj < 8; ++jj) {
            float f0 = tileF[(c * 16 + 2 * jj + 0) * 65 + d];
            float f1 = tileF[(c * 16 + 2 * jj + 1) * 65 + d];
            pk[jj] = (unsigned int)f2bf(f0) | ((unsigned int)f2bf(f1) << 16);
        }
        uint4 u0 = make_uint4(pk[0], pk[1], pk[2], pk[3]);
        uint4 u1 = make_uint4(pk[4], pk[5], pk[6], pk[7]);
        ((uint4*)&vtile[d * 72 + c * 16])[0] = u0;
        ((uint4*)&vtile[d * 72 + c * 16 + 8])[0] = u1;
        unsigned short* outp = vt + ((long)(bh * 64 + d)) * S_ + s0 + c * 16;
        ((uint4*)outp)[0] = u0;
        ((uint4*)outp)[1] = u1;
    }
    __syncthreads();   // tileF free
    // ---- dump k-hat regs -> tileF
#pragma unroll
    for (int it = 0; it < 4; ++it) {
        int f  = it * 256 + t;
        int sl = f >> 4, d4 = f & 15;
        tileF[sl * 65 + d4 * 4 + 0] = kreg[it][0];
        tileF[sl * 65 + d4 * 4 + 1] = kreg[it][1];
        tileF[sl * 65 + d4 * 4 + 2] = kreg[it][2];
        tileF[sl * 65 + d4 * 4 + 3] = kreg[it][3];
    }
    __syncthreads();
    // ---- pack K^T -> ktile (LDS only) [proven]
    {
        unsigned int pk[8];
#pragma unroll
        for (int jj = 0; jj < 8; ++jj) {
            float f0 = tileF[(c * 16 + 2 * jj + 0) * 65 + d];
            float f1 = tileF[(c * 16 + 2 * jj + 1) * 65 + d];
            pk[jj] = (unsigned int)f2bf(f0) | ((unsigned int)f2bf(f1) << 16);
        }
        ((uint4*)&ktile[d * 72 + c * 16])[0] = make_uint4(pk[0], pk[1], pk[2], pk[3]);
        ((uint4*)&ktile[d * 72 + c * 16 + 8])[0] = make_uint4(pk[4], pk[5], pk[6], pk[7]);
    }
    __syncthreads();

    // ---- G = V^T x K  [identical proven MFMA body]
    int w = t >> 6, lane = t & 63, quad = lane >> 4, l16 = lane & 15;
    f32x4_t accS[4];
#pragma unroll
    for (int dkt = 0; dkt < 4; ++dkt) accS[dkt] = (f32x4_t){0.f, 0.f, 0.f, 0.f};

    bf16x8_t aV[2], bK[4][2];
#pragma unroll
    for (int sst = 0; sst < 2; ++sst)
        aV[sst] = *(const bf16x8_t*)&vtile[(w * 16 + l16) * 72 + sst * 32 + quad * 8];
#pragma unroll
    for (int dkt = 0; dkt < 4; ++dkt)
#pragma unroll
        for (int sst = 0; sst < 2; ++sst)
            bK[dkt][sst] = *(const bf16x8_t*)&ktile[(dkt * 16 + l16) * 72 + sst * 32 + quad * 8];
#pragma unroll
    for (int dkt = 0; dkt < 4; ++dkt)
#pragma unroll
        for (int sst = 0; sst < 2; ++sst)
            accS[dkt] = __builtin_amdgcn_mfma_f32_16x16x32_bf16(aV[sst], bK[dkt][sst], accS[dkt], 0, 0, 0);

    unsigned short* Gp = Gg + (long)idx * 4096;
#pragma unroll
    for (int dkt = 0; dkt < 4; ++dkt)
#pragma unroll
        for (int r = 0; r < 4; ++r)
            Gp[(w * 16 + quad * 4 + r) * 64 + dkt * 16 + l16] = f2bf(accS[dkt][r]);
}

// ---------------- kernel 2: scan — elementwise prefix over 32 chunks (proven R8/R10) ----
__global__ __launch_bounds__(256) void scan_kernel(const unsigned short* __restrict__ Gg,
                                                   unsigned short* __restrict__ Sg) {
    int tid = blockIdx.x * 256 + threadIdx.x;   // 0..131071
    int bh  = tid >> 12;
    int e   = tid & 4095;
    long base = ((long)bh * 32) * 4096 + e;
    float acc = 0.0f;
#pragma unroll
    for (int j = 0; j < 32; ++j) {
        if (j > 0) Sg[base + (long)j * 4096] = f2bf(acc);
        acc += bf2f(Gg[base + (long)j * 4096]);
    }
}

// ---------------- kernel 3: outc — per-(bh,chunk) output (verbatim R10) ------
__global__ __launch_bounds__(256) void outc_kernel(const float* __restrict__ Q,
                                                   const unsigned short* __restrict__ kb,
                                                   const unsigned short* __restrict__ vt,
                                                   const unsigned short* __restrict__ Sg,
                                                   float* __restrict__ out) {
    __shared__ __align__(16) unsigned short strip[4][16 * 72];
    int t = threadIdx.x;
    int w = t >> 6, lane = t & 63, quad = lane >> 4, l16 = lane & 15;
    int idx = blockIdx.x;
    int bh  = idx & 31;
    int tch = idx >> 5;
    int b = bh >> 4, hh = bh & 15;

    const unsigned short* kB = kb + ((long)(b * S_ + tch * 64)) * 1024 + hh * 64;
    const unsigned short* vB = vt + (long)bh * 64 * S_ + tch * 64;
    const unsigned short* SB = Sg + ((long)(bh * 32 + tch)) * 4096;

    float lnv = -3.4657359027997265f + (float)hh * (-0.18483924814931874f);
    float l2g = log2f(1.0f - expf(lnv));
    int qrow = w * 16 + l16;
    float pos = (float)(tch * 64 + qrow);
    float gs = exp2f(pos * l2g);
    const float* Qp = Q + ((long)(b * S_ + tch * 64 + qrow)) * 1024 + hh * 64;

    bf16x8_t aQ[2];
#pragma unroll
    for (int kk = 0; kk < 2; ++kk) {
        int d0 = kk * 32 + quad * 8;
        float4 x0 = *(const float4*)(Qp + d0);
        float4 x1 = *(const float4*)(Qp + d0 + 4);
        float xs0 = x0.x, xs1 = x0.y, xs2 = x0.z, xs3 = x0.w;
        float xs4 = x1.x, xs5 = x1.y, xs6 = x1.z, xs7 = x1.w;
        bf16x8_t q;
#pragma unroll
        for (int p = 0; p < 4; ++p) {
            float cv, sv;
            rotpair(d0 / 2 + p, pos, cv, sv, false);
            float cq = cv * gs, sq = sv * gs;
            float xe = (p == 0) ? xs0 : (p == 1) ? xs2 : (p == 2) ? xs4 : xs6;
            float xo = (p == 0) ? xs1 : (p == 1) ? xs3 : (p == 2) ? xs5 : xs7;
            q[2 * p]     = (short)f2bf(xe * cq - xo * sq);
            q[2 * p + 1] = (short)f2bf(xo * cq + xe * sq);
        }
        aQ[kk] = q;
    }

    f32x4_t accO[4];
#pragma unroll
    for (int dvt = 0; dvt < 4; ++dvt) accO[dvt] = (f32x4_t){0.f, 0.f, 0.f, 0.f};

    if (tch > 0) {
#pragma unroll
        for (int dvt = 0; dvt < 4; ++dvt)
#pragma unroll
            for (int kk = 0; kk < 2; ++kk) {
                bf16x8_t bS = *(const bf16x8_t*)(SB + (dvt * 16 + l16) * 64 + kk * 32 + quad * 8);
                accO[dvt] = __builtin_amdgcn_mfma_f32_16x16x32_bf16(aQ[kk], bS, accO[dvt], 0, 0, 0);
            }
    }

    unsigned short* sw = strip[w];
    for (int st = w + 1; st < 4; ++st)
        *(uint2*)&sw[l16 * 72 + st * 16 + quad * 4] = make_uint2(0u, 0u);

    for (int st = 0; st <= w; ++st) {
        f32x4_t pp = (f32x4_t){0.f, 0.f, 0.f, 0.f};
#pragma unroll
        for (int kk = 0; kk < 2; ++kk) {
            bf16x8_t aK = *(const bf16x8_t*)(kB + (long)(st * 16 + l16) * 1024 + kk * 32 + quad * 8);
            pp = __builtin_amdgcn_mfma_f32_16x16x32_bf16(aK, aQ[kk], pp, 0, 0, 0);
        }
        if (st == w) {
#pragma unroll
            for (int r = 0; r < 4; ++r)
                if (quad * 4 + r > l16) pp[r] = 0.0f;   // keep iff q >= s'
        }
        uint2 pk2;
        pk2.x = (unsigned)f2bf(pp[0]) | ((unsigned)f2bf(pp[1]) << 16);
        pk2.y = (unsigned)f2bf(pp[2]) | ((unsigned)f2bf(pp[3]) << 16);
        *(uint2*)&sw[l16 * 72 + st * 16 + quad * 4] = pk2;
    }

    bf16x8_t aP0 = *(const bf16x8_t*)&sw[l16 * 72 + 0 * 32 + quad * 8];
#pragma unroll
    for (int dvt = 0; dvt < 4; ++dvt) {
        bf16x8_t bV0 = *(const bf16x8_t*)(vB + (long)(dvt * 16 + l16) * S_ + 0 * 32 + quad * 8);
        accO[dvt] = __builtin_amdgcn_mfma_f32_16x16x32_bf16(aP0, bV0, accO[dvt], 0, 0, 0);
    }
    if (w >= 2) {
        bf16x8_t aP1 = *(const bf16x8_t*)&sw[l16 * 72 + 1 * 32 + quad * 8];
#pragma unroll
        for (int dvt = 0; dvt < 4; ++dvt) {
            bf16x8_t bV1 = *(const bf16x8_t*)(vB + (long)(dvt * 16 + l16) * S_ + 1 * 32 + quad * 8);
            accO[dvt] = __builtin_amdgcn_mfma_f32_16x16x32_bf16(aP1, bV1, accO[dvt], 0, 0, 0);
        }
    }

#pragma unroll
    for (int dvt = 0; dvt < 4; ++dvt)
#pragma unroll
        for (int r = 0; r < 4; ++r) {
            int row = tch * 64 + w * 16 + quad * 4 + r;
            out[((long)(b * S_ + row)) * 1024 + hh * 64 + dvt * 16 + l16] = accO[dvt][r];
        }
}

extern "C" void kernel_launch(void* const* d_in, const int* in_sizes, int n_in,
                              void* d_out, int out_size, void* d_ws, size_t ws_size,
                              hipStream_t stream) {
    const float* Q = (const float*)d_in[0];
    const float* K = (const float*)d_in[1];
    const float* V = (const float*)d_in[2];
    float* out = (float*)d_out;

    const size_t perBuf = (size_t)B_ * H_ * S_ * D_;   // 4.19M shorts = 8.4 MB
    unsigned short* kb = (unsigned short*)d_ws;
    unsigned short* vt = kb + perBuf;
    unsigned short* Sg = vt + perBuf;
    unsigned short* Gg = Sg + perBuf;

    hipLaunchKernelGGL(gkv_kernel,  dim3(1024), dim3(256), 0, stream, K, V, kb, vt, Gg);
    hipLaunchKernelGGL(scan_kernel, dim3(512),  dim3(256), 0, stream, Gg, Sg);
    hipLaunchKernelGGL(outc_kernel, dim3(1024), dim3(256), 0, stream, Q, kb, vt, Sg, out);
}